// Round 4
// baseline (335.910 us; speedup 1.0000x reference)
//
#include <hip/hip_runtime.h>
#include <hip/hip_bf16.h>
#include <math.h>

#define N 8192
#define D 1024
#define C 1000
#define CP 1024
#define INV_T (1.0f / 0.3f)

typedef __bf16 bf16_t;
typedef bf16_t bf16x8 __attribute__((ext_vector_type(8)));
typedef float f32x4 __attribute__((ext_vector_type(4)));

typedef __attribute__((address_space(3))) uint32_t lds_u32_t;
typedef const __attribute__((address_space(1))) uint32_t glb_u32_t;

// ---------------- prep: normalize rows (+hist) and cast W, one dispatch ----------------
__global__ void prep_kernel(const float* __restrict__ feat, const int* __restrict__ labels,
                            const float* __restrict__ W,
                            float* __restrict__ norms, bf16_t* __restrict__ feat_n,
                            bf16_t* __restrict__ Wp, int* __restrict__ hist) {
  int g = blockIdx.x;
  int t = threadIdx.x;
  if (g < N) {
    int row = g;
    const float4* fr = (const float4*)(feat + (size_t)row * D);
    float4 x = fr[t];
    float ss = x.x * x.x + x.y * x.y + x.z * x.z + x.w * x.w;
    for (int off = 32; off; off >>= 1) ss += __shfl_down(ss, off, 64);
    __shared__ float sred[4];
    __shared__ float srn;
    int lane = t & 63, w = t >> 6;
    if (lane == 0) sred[w] = ss;
    __syncthreads();
    if (t == 0) {
      float tot = sred[0] + sred[1] + sred[2] + sred[3];
      float nrm = sqrtf(tot);
      norms[row] = nrm;
      srn = 1.0f / nrm;
      atomicAdd(&hist[labels[row]], 1);
    }
    __syncthreads();
    float rn = srn;
    union { bf16_t h[4]; uint2 u; } pk;
    pk.h[0] = (bf16_t)(x.x * rn);
    pk.h[1] = (bf16_t)(x.y * rn);
    pk.h[2] = (bf16_t)(x.z * rn);
    pk.h[3] = (bf16_t)(x.w * rn);
    *(uint2*)(feat_n + (size_t)row * D + t * 4) = pk.u;
  } else {
    int row = g - N;
    union { bf16_t h[4]; uint2 u; } pk;
    if (row < C) {
      float4 x = ((const float4*)(W + (size_t)row * D))[t];
      pk.h[0] = (bf16_t)x.x; pk.h[1] = (bf16_t)x.y;
      pk.h[2] = (bf16_t)x.z; pk.h[3] = (bf16_t)x.w;
    } else {
      pk.h[0] = pk.h[1] = pk.h[2] = pk.h[3] = (bf16_t)0.0f;
    }
    *(uint2*)(Wp + (size_t)row * D + t * 4) = pk.u;
  }
}

// ---------------- GEMM tile geometry ----------------
#define BM 128
#define BN 128
#define BK 32
#define NSIM 2080   // 64*65/2 upper-triangle blocks
#define NLOG 512    // 64 x 8 logits blocks
// LDS tile: 128 rows x 32 bf16 = 8 KB = 512 chunks of 16 B, NO padding
// (global_load_lds dest = wave-uniform base + lane*16). XOR chunk swizzle
// (R2-verified, SQ_LDS_BANK_CONFLICT == 0): chunk c of row r lives at
// c ^ ((r>>1)&3); frag-read aliasing is 2-way max (free, m136).

__device__ __forceinline__ void stage_tile(const bf16_t* __restrict__ g0,
                                           bf16_t* lds, int t, int w) {
#pragma unroll
  for (int p = 0; p < 2; p++) {
    int chunk = p * 256 + t;               // 0..511
    int r = chunk >> 2;                    // tile row 0..127
    int c = (chunk & 3) ^ ((r >> 1) & 3);  // global 16B-chunk within row
    const bf16_t* gp = g0 + (size_t)r * D + c * 8;
    bf16_t* lp = lds + (size_t)(p * 256 + w * 64) * 8;  // wave-uniform base
    __builtin_amdgcn_global_load_lds((glb_u32_t*)gp, (lds_u32_t*)lp, 16, 0, 0);
  }
}

// one fused kernel: g < NSIM -> sim block (upper triangle), else logits block
// logits blocks also accumulate per-row CE exp-sums + capture label logit.
__launch_bounds__(256)
__global__ void mega_gemm(const bf16_t* __restrict__ A, const bf16_t* __restrict__ Wp,
                          const int* __restrict__ labels,
                          const float* __restrict__ norms, const float* __restrict__ bias,
                          float* __restrict__ S, float* __restrict__ P,
                          float* __restrict__ ceS, float* __restrict__ lab_logit,
                          float* __restrict__ out) {
  __shared__ __align__(16) bf16_t As[BM * BK];
  __shared__ __align__(16) bf16_t Bs[BN * BK];
  int g = blockIdx.x;
  int t = threadIdx.x;
  int lane = t & 63;
  int w = t >> 6;
  int wm = (w & 1) << 6;
  int wn = (w >> 1) << 6;
  int l15 = lane & 15;
  int quad = lane >> 4;
  f32x4 acc[4][4] = {};

  bool is_sim = (g < NSIM);
  int tileM, tileN;
  bool diag = false;
  if (is_sim) {
    const int nb = N / BM;
    float fnb = (float)nb + 0.5f;
    int bi = (int)(fnb - sqrtf(fnb * fnb - 2.0f * (float)g));
    if (bi < 0) bi = 0;
#define TRI_OFF(r) ((r) * nb - (r) * ((r)-1) / 2)
    while (TRI_OFF(bi + 1) <= g) bi++;
    while (TRI_OFF(bi) > g) bi--;
    int bj = bi + (g - TRI_OFF(bi));
#undef TRI_OFF
    tileM = bi * BM;
    tileN = bj * BN;
    diag = (bi == bj);
  } else {
    int lg = g - NSIM;
    tileM = (lg >> 3) * BM;   // 0..63
    tileN = (lg & 7) * BN;    // 0..7
  }

  const bf16_t* Abase = A + (size_t)tileM * D;
  const bf16_t* Bbase = (is_sim ? A : Wp) + (size_t)tileN * D;

  for (int k0 = 0; k0 < D; k0 += BK) {
    stage_tile(Abase + k0, As, t, w);
    stage_tile(Bbase + k0, Bs, t, w);
    __syncthreads();
    bf16x8 af[4], bfr[4];
#pragma unroll
    for (int i = 0; i < 4; i++) {
      int ar = wm + i * 16 + l15;
      int cc = quad ^ ((ar >> 1) & 3);
      af[i] = *(const bf16x8*)(&As[ar * BK + cc * 8]);
    }
#pragma unroll
    for (int j = 0; j < 4; j++) {
      int br = wn + j * 16 + l15;
      int cc = quad ^ ((br >> 1) & 3);
      bfr[j] = *(const bf16x8*)(&Bs[br * BK + cc * 8]);
    }
#pragma unroll
    for (int i = 0; i < 4; i++)
#pragma unroll
      for (int j = 0; j < 4; j++)
        acc[i][j] = __builtin_amdgcn_mfma_f32_16x16x32_bf16(af[i], bfr[j], acc[i][j], 0, 0, 0);
    __syncthreads();
  }

  if (is_sim) {
    int gcj[4], lc[4];
#pragma unroll
    for (int j = 0; j < 4; j++) {
      gcj[j] = tileN + wn + j * 16 + l15;
      lc[j] = labels[gcj[j]];
    }
    float csS[4] = {0.f, 0.f, 0.f, 0.f}, csP[4] = {0.f, 0.f, 0.f, 0.f};
#pragma unroll
    for (int i = 0; i < 4; i++) {
#pragma unroll
      for (int r = 0; r < 4; r++) {
        int gr = tileM + wm + i * 16 + quad * 4 + r;
        int lr = labels[gr];
        float ssum = 0.0f, psum = 0.0f;
#pragma unroll
        for (int j = 0; j < 4; j++) {
          float sim = acc[i][j][r] * INV_T;
          if (gcj[j] != gr) {
            float e = __expf(sim);
            float pv = (lc[j] == lr) ? sim : 0.0f;
            ssum += e;
            psum += pv;
            csS[j] += e;
            csP[j] += pv;
          }
        }
        for (int m = 1; m < 16; m <<= 1) {
          ssum += __shfl_xor(ssum, m, 64);
          psum += __shfl_xor(psum, m, 64);
        }
        if (l15 == 0) {
          atomicAdd(&S[gr], ssum);
          atomicAdd(&P[gr], psum);
        }
      }
    }
    if (!diag) {
#pragma unroll
      for (int j = 0; j < 4; j++) {
        csS[j] += __shfl_xor(csS[j], 16, 64);
        csS[j] += __shfl_xor(csS[j], 32, 64);
        csP[j] += __shfl_xor(csP[j], 16, 64);
        csP[j] += __shfl_xor(csP[j], 32, 64);
        if (quad == 0) {
          atomicAdd(&S[gcj[j]], csS[j]);
          atomicAdd(&P[gcj[j]], csP[j]);
        }
      }
    }
  } else {
    // logits epilogue + fused CE accumulation (exp-sum per row, label logit)
#pragma unroll
    for (int i = 0; i < 4; i++) {
#pragma unroll
      for (int r = 0; r < 4; r++) {
        int gr = tileM + wm + i * 16 + quad * 4 + r;
        float nrm = norms[gr];
        int lab = labels[gr];
        float esum = 0.0f;
#pragma unroll
        for (int j = 0; j < 4; j++) {
          int gc = tileN + wn + j * 16 + l15;
          if (gc < C) {
            float lg = nrm * acc[i][j][r] + bias[gc];
            out[(size_t)gr * C + gc] = lg;
            esum += __expf(lg);
            if (gc == lab) lab_logit[gr] = lg;
          }
        }
        for (int m = 1; m < 16; m <<= 1) esum += __shfl_xor(esum, m, 64);
        if (l15 == 0) atomicAdd(&ceS[gr], esum);
      }
    }
  }
}

// ---------------- final: CE mean + SCL assembly + loss ----------------
__global__ void final_kernel(const float* __restrict__ S, const float* __restrict__ P,
                             const int* __restrict__ labels, const int* __restrict__ hist,
                             const float* __restrict__ ceS, const float* __restrict__ lab_logit,
                             float* __restrict__ out) {
  int t = threadIdx.x;
  float lsum = 0.0f, lval = 0.0f, cesum = 0.0f;
  for (int i = t; i < N; i += 256) {
    cesum += logf(ceS[i]) - lab_logit[i];
    int cnt = hist[labels[i]] - 1;
    if (cnt > 0) {
      float bl = logf(S[i]);
      float per = -(P[i] - (float)cnt * bl) / (float)cnt;
      lsum += per;
      lval += 1.0f;
    }
  }
  for (int off = 32; off; off >>= 1) {
    lsum += __shfl_down(lsum, off, 64);
    lval += __shfl_down(lval, off, 64);
    cesum += __shfl_down(cesum, off, 64);
  }
  __shared__ float ss[4], sv[4], sc[4];
  int lane = t & 63, w = t >> 6;
  if (lane == 0) { ss[w] = lsum; sv[w] = lval; sc[w] = cesum; }
  __syncthreads();
  if (t == 0) {
    float sum = ss[0] + ss[1] + ss[2] + ss[3];
    float nv = sv[0] + sv[1] + sv[2] + sv[3];
    float ce = (sc[0] + sc[1] + sc[2] + sc[3]) * (1.0f / (float)N);
    float scl = (nv > 0.0f) ? sum / nv : 0.0f;
    out[(size_t)N * C] = 0.9f * ce + 0.1f * scl;
  }
}

extern "C" void kernel_launch(void* const* d_in, const int* in_sizes, int n_in,
                              void* d_out, int out_size, void* d_ws, size_t ws_size,
                              hipStream_t stream) {
  const float* feat   = (const float*)d_in[0];
  const int*   labels = (const int*)d_in[1];
  const float* W      = (const float*)d_in[2];
  const float* b      = (const float*)d_in[3];
  float* out = (float*)d_out;  // [N*C logits, 1 loss]

  char* ws = (char*)d_ws;
  bf16_t* feat_n = (bf16_t*)ws;                                   // N*D*2  = 16.78 MB
  bf16_t* Wp     = (bf16_t*)(ws + (size_t)N * D * 2);             // CP*D*2 =  2.10 MB
  float*  norms  = (float*)(ws + (size_t)N * D * 2 + (size_t)CP * D * 2);
  float*  S      = norms + N;        // zeroed region starts here
  float*  P      = S + N;
  float*  ceS    = P + N;
  int*    hist   = (int*)(ceS + N);  // 1024 ints, zeroed
  float*  lab_logit = (float*)(hist + 1024);  // written unconditionally

  size_t zero_bytes = (size_t)((char*)(hist + 1024) - (char*)S);
  hipMemsetAsync(S, 0, zero_bytes, stream);

  prep_kernel<<<N + CP, 256, 0, stream>>>(feat, labels, W, norms, feat_n, Wp, hist);
  mega_gemm<<<NSIM + NLOG, 256, 0, stream>>>(feat_n, Wp, labels, norms, b,
                                             S, P, ceS, lab_logit, out);
  final_kernel<<<1, 256, 0, stream>>>(S, P, labels, hist, ceS, lab_logit, out);
}